// Round 5
// baseline (449.453 us; speedup 1.0000x reference)
//
#include <hip/hip_runtime.h>

#define F_IN 128
#define HID 64
#define HEADS 4
#define NC 8

// ---------------------------------------------------------------- helpers

__device__ __forceinline__ ushort f2bf(float f) {      // RNE round to bf16
    uint u = __float_as_uint(f);
    return (ushort)((u + 0x7fffu + ((u >> 16) & 1u)) >> 16);
}
__device__ __forceinline__ float bf2f(ushort h) {
    return __uint_as_float(((uint)h) << 16);
}
__device__ __forceinline__ float edgew(float e) {      // exp(leaky_relu(e, 0.2))
    e = (e > 0.f) ? e : 0.2f * e;
    return __expf(e);
}

// ---------------------------------------------------------------- init / CSR

__global__ void k_init(int* __restrict__ deg, int N, int* __restrict__ counts, int NG) {
    int i = blockIdx.x * blockDim.x + threadIdx.x;
    if (i < N) deg[i] = 1;              // self loop contributes 1
    if (i < NG) counts[i] = 0;
}

// fused: edge degree count + batch count (grid covers max(E,N))
__global__ void k_count(const int* __restrict__ ei, int E, int* __restrict__ deg,
                        const int* __restrict__ batch, int N, int* __restrict__ counts) {
    int i = blockIdx.x * blockDim.x + threadIdx.x;
    if (i < E) atomicAdd(&deg[ei[E + i]], 1);   // dst row
    if (i < N) atomicAdd(&counts[batch[i]], 1);
}

// hierarchical scan: part (per 1024-block excl + block total), bsum scan, add
__global__ __launch_bounds__(1024) void k_scan_part(const int* __restrict__ v,
                                                    int* __restrict__ excl,
                                                    int* __restrict__ bsum, int n) {
    __shared__ int buf[1024];
    int tid = threadIdx.x;
    int i = blockIdx.x * 1024 + tid;
    int val = (i < n) ? v[i] : 0;
    buf[tid] = val;
    __syncthreads();
    for (int off = 1; off < 1024; off <<= 1) {
        int t = (tid >= off) ? buf[tid - off] : 0;
        __syncthreads();
        buf[tid] += t;
        __syncthreads();
    }
    if (i < n) excl[i] = buf[tid] - val;
    if (tid == 1023) bsum[blockIdx.x] = buf[1023];
}

__global__ __launch_bounds__(1024) void k_scan_bsum(const int* __restrict__ bsum,
                                                    int* __restrict__ boff, int nb,
                                                    int* __restrict__ total_out) {
    __shared__ int buf[1024];
    int tid = threadIdx.x;
    int val = (tid < nb) ? bsum[tid] : 0;
    buf[tid] = val;
    __syncthreads();
    for (int off = 1; off < 1024; off <<= 1) {
        int t = (tid >= off) ? buf[tid - off] : 0;
        __syncthreads();
        buf[tid] += t;
        __syncthreads();
    }
    if (tid < nb) boff[tid] = buf[tid] - val;
    if (tid == 1023) total_out[0] = buf[1023];
}

// finalize rowstart (+= block offset) AND seed csr with self-loop + cursor=1
__global__ void k_scan_add_self(int* __restrict__ rowstart, const int* __restrict__ boff,
                                int* __restrict__ cursor, int* __restrict__ csr, int n) {
    int i = blockIdx.x * blockDim.x + threadIdx.x;
    if (i < n) {
        int rs = rowstart[i] + boff[i >> 10];
        rowstart[i] = rs;
        csr[rs] = i;          // self loop first
        cursor[i] = 1;
    }
}

// single-block scan for small arrays (NG=512); writes excl[0..n]
__global__ __launch_bounds__(1024) void k_scan(const int* __restrict__ v, int* __restrict__ excl, int n) {
    __shared__ int buf[1024];
    int tid = threadIdx.x;
    int val = (tid < n) ? v[tid] : 0;
    buf[tid] = val;
    __syncthreads();
    for (int off = 1; off < 1024; off <<= 1) {
        int t = (tid >= off) ? buf[tid - off] : 0;
        __syncthreads();
        buf[tid] += t;
        __syncthreads();
    }
    if (tid < n) excl[tid] = buf[tid] - val;
    if (tid == 1023) excl[n] = buf[1023];
}

__global__ void k_scatter(const int* __restrict__ ei, int E, const int* __restrict__ rowstart,
                          int* __restrict__ cursor, int* __restrict__ csr) {
    int e = blockIdx.x * blockDim.x + threadIdx.x;
    if (e < E) {
        int d = ei[E + e], s = ei[e];
        int pos = atomicAdd(&cursor[d], 1);
        csr[rowstart[d] + pos] = s;
    }
}

// ---------------------------------------------------------------- layer-1 GEMM + fused att
// h1 = x[N][128] @ W1[128][256]. Block: 32 rows x 256 cols; thread: 8 rows x 4 cols.
// rg = tid>>6 (wave-uniform) -> x-tile reads are broadcast (conflict-free).
__global__ __launch_bounds__(256) void k_gemm1(const float* __restrict__ x,
                                               const float* __restrict__ W1,
                                               const float* __restrict__ atts,
                                               const float* __restrict__ attd,
                                               ushort* __restrict__ h1b,
                                               float* __restrict__ as1, float* __restrict__ ad1,
                                               int N) {
    __shared__ float xs[32][136];      // stride 136: 16B-aligned b128 rows
    __shared__ float wt[32][256];
    int n0 = blockIdx.x * 32;
    int tid = threadIdx.x;
    // stage full x tile once: 32 rows x 128 cols = 1024 float4, 4 per thread
    #pragma unroll
    for (int i = 0; i < 4; i++) {
        int f = tid + i * 256;
        int row = f >> 5, c4 = (f & 31) * 4;
        float4 v = {0.f, 0.f, 0.f, 0.f};
        if (n0 + row < N) v = *(const float4*)(x + (size_t)(n0 + row) * F_IN + c4);
        *(float4*)&xs[row][c4] = v;
    }
    int rg = tid >> 6, cg = tid & 63;
    int c0 = cg * 4;
    float acc[8][4];
    #pragma unroll
    for (int r = 0; r < 8; r++)
        #pragma unroll
        for (int c = 0; c < 4; c++) acc[r][c] = 0.f;

    for (int kt = 0; kt < F_IN; kt += 32) {
        __syncthreads();               // wt safe to overwrite (and xs visible, 1st iter)
        #pragma unroll
        for (int i = 0; i < 8; i++) {  // stage W tile: 32 x 256 = 2048 float4
            int f = tid + i * 256;
            int k = f >> 6, c4 = (f & 63) * 4;
            *(float4*)&wt[k][c4] = *(const float4*)(W1 + (size_t)(kt + k) * 256 + c4);
        }
        __syncthreads();
        #pragma unroll
        for (int k = 0; k < 32; k += 4) {
            float4 wv[4];
            #pragma unroll
            for (int kk = 0; kk < 4; kk++) wv[kk] = *(float4*)&wt[k + kk][c0];
            #pragma unroll
            for (int r = 0; r < 8; r++) {
                float4 xv = *(float4*)&xs[rg * 8 + r][kt + k];   // wave-uniform broadcast
                acc[r][0] += xv.x * wv[0].x + xv.y * wv[1].x + xv.z * wv[2].x + xv.w * wv[3].x;
                acc[r][1] += xv.x * wv[0].y + xv.y * wv[1].y + xv.z * wv[2].y + xv.w * wv[3].y;
                acc[r][2] += xv.x * wv[0].z + xv.y * wv[1].z + xv.z * wv[2].z + xv.w * wv[3].z;
                acc[r][3] += xv.x * wv[0].w + xv.y * wv[1].w + xv.z * wv[2].w + xv.w * wv[3].w;
            }
        }
    }
    // epilogue: bf16 h1 store + fused att coefs (reduce 16 lanes x 4 cols = 64 ch/head)
    int head = cg >> 4;
    float a0 = atts[c0], a1 = atts[c0 + 1], a2 = atts[c0 + 2], a3 = atts[c0 + 3];
    float d0 = attd[c0], d1 = attd[c0 + 1], d2 = attd[c0 + 2], d3 = attd[c0 + 3];
    #pragma unroll
    for (int r = 0; r < 8; r++) {
        int n = n0 + rg * 8 + r;
        float s = acc[r][0] * a0 + acc[r][1] * a1 + acc[r][2] * a2 + acc[r][3] * a3;
        float d = acc[r][0] * d0 + acc[r][1] * d1 + acc[r][2] * d2 + acc[r][3] * d3;
        #pragma unroll
        for (int off = 1; off < 16; off <<= 1) {
            s += __shfl_xor(s, off);
            d += __shfl_xor(d, off);
        }
        if (n < N) {
            ushort4 hv;
            hv.x = f2bf(acc[r][0]); hv.y = f2bf(acc[r][1]);
            hv.z = f2bf(acc[r][2]); hv.w = f2bf(acc[r][3]);
            *(ushort4*)(h1b + (size_t)n * 256 + c0) = hv;
            if ((cg & 15) == 0) { as1[n * 4 + head] = s; ad1[n * 4 + head] = d; }
        }
    }
}

// ---------------------------------------------------------------- layer-2 GEMM + fused att
// h2 = out1[N][256] @ W2[256][64]. Block: 128 rows x 64 cols; thread: 8 rows x 4 cols.
__global__ __launch_bounds__(256) void k_gemm2(const float* __restrict__ xin,
                                               const float* __restrict__ W2,
                                               const float* __restrict__ atts,
                                               const float* __restrict__ attd,
                                               ushort* __restrict__ h2b,
                                               float* __restrict__ as2, float* __restrict__ ad2,
                                               int N) {
    __shared__ float xs[128][72];      // 72: 16B-aligned rows
    __shared__ float wt[64][64];
    int n0 = blockIdx.x * 128;
    int tid = threadIdx.x;
    int rg = tid >> 4, cg = tid & 15;
    int c0 = cg * 4;
    float acc[8][4];
    #pragma unroll
    for (int r = 0; r < 8; r++)
        #pragma unroll
        for (int c = 0; c < 4; c++) acc[r][c] = 0.f;

    for (int kt = 0; kt < 256; kt += 64) {
        __syncthreads();
        #pragma unroll
        for (int i = 0; i < 8; i++) {  // stage x: 128 rows x 64 cols = 2048 float4
            int f = tid + i * 256;
            int row = f >> 4, c4 = (f & 15) * 4;
            float4 v = {0.f, 0.f, 0.f, 0.f};
            if (n0 + row < N) v = *(const float4*)(xin + (size_t)(n0 + row) * 256 + kt + c4);
            *(float4*)&xs[row][c4] = v;
        }
        #pragma unroll
        for (int i = 0; i < 4; i++) {  // stage W: 64 x 64 = 1024 float4
            int f = tid + i * 256;
            int k = f >> 4, c4 = (f & 15) * 4;
            *(float4*)&wt[k][c4] = *(const float4*)(W2 + (size_t)(kt + k) * 64 + c4);
        }
        __syncthreads();
        #pragma unroll
        for (int k = 0; k < 64; k += 4) {
            float4 wv[4];
            #pragma unroll
            for (int kk = 0; kk < 4; kk++) wv[kk] = *(float4*)&wt[k + kk][c0];
            #pragma unroll
            for (int r = 0; r < 8; r++) {
                float4 xv = *(float4*)&xs[rg * 8 + r][k];
                acc[r][0] += xv.x * wv[0].x + xv.y * wv[1].x + xv.z * wv[2].x + xv.w * wv[3].x;
                acc[r][1] += xv.x * wv[0].y + xv.y * wv[1].y + xv.z * wv[2].y + xv.w * wv[3].y;
                acc[r][2] += xv.x * wv[0].z + xv.y * wv[1].z + xv.z * wv[2].z + xv.w * wv[3].z;
                acc[r][3] += xv.x * wv[0].w + xv.y * wv[1].w + xv.z * wv[2].w + xv.w * wv[3].w;
            }
        }
    }
    // epilogue: bf16 h2 store + fused att coefs (reduce 16 lanes x 4 cols = 64 ch)
    float a0 = atts[c0], a1 = atts[c0 + 1], a2 = atts[c0 + 2], a3 = atts[c0 + 3];
    float d0 = attd[c0], d1 = attd[c0 + 1], d2 = attd[c0 + 2], d3 = attd[c0 + 3];
    #pragma unroll
    for (int r = 0; r < 8; r++) {
        int n = n0 + rg * 8 + r;
        float s = acc[r][0] * a0 + acc[r][1] * a1 + acc[r][2] * a2 + acc[r][3] * a3;
        float d = acc[r][0] * d0 + acc[r][1] * d1 + acc[r][2] * d2 + acc[r][3] * d3;
        #pragma unroll
        for (int off = 1; off < 16; off <<= 1) {
            s += __shfl_xor(s, off);
            d += __shfl_xor(d, off);
        }
        if (n < N) {
            ushort4 hv;
            hv.x = f2bf(acc[r][0]); hv.y = f2bf(acc[r][1]);
            hv.z = f2bf(acc[r][2]); hv.w = f2bf(acc[r][3]);
            *(ushort4*)(h2b + (size_t)n * 64 + c0) = hv;
            if (cg == 0) { as2[n] = s; ad2[n] = d; }
        }
    }
}

// ---------------------------------------------------------------- aggregation (1 wave / node)

__global__ __launch_bounds__(256) void k_agg1(const ushort* __restrict__ h1b,
                                              const float* __restrict__ as, const float* __restrict__ ad,
                                              const int* __restrict__ rowstart, const int* __restrict__ csr,
                                              const float* __restrict__ b1,
                                              float* __restrict__ out1, int N) {
    int n = blockIdx.x * 4 + (threadIdx.x >> 6);
    int lane = threadIdx.x & 63;
    if (n >= N) return;
    int head = lane >> 4;
    int coff = lane * 4;
    float adv = ad[n * 4 + head];
    int beg = rowstart[n], end = rowstart[n + 1];
    float a0 = 0.f, a1 = 0.f, a2 = 0.f, a3 = 0.f, ssum = 0.f;
    int j = beg;
    for (; j + 4 <= end; j += 4) {
        int s0 = csr[j + 0], s1 = csr[j + 1], s2 = csr[j + 2], s3 = csr[j + 3];
        float e0 = as[s0 * 4 + head], e1 = as[s1 * 4 + head];
        float e2 = as[s2 * 4 + head], e3 = as[s3 * 4 + head];
        ushort4 v0 = *(const ushort4*)(h1b + (size_t)s0 * 256 + coff);
        ushort4 v1 = *(const ushort4*)(h1b + (size_t)s1 * 256 + coff);
        ushort4 v2 = *(const ushort4*)(h1b + (size_t)s2 * 256 + coff);
        ushort4 v3 = *(const ushort4*)(h1b + (size_t)s3 * 256 + coff);
        float w0 = edgew(e0 + adv), w1 = edgew(e1 + adv);
        float w2 = edgew(e2 + adv), w3 = edgew(e3 + adv);
        ssum += (w0 + w1) + (w2 + w3);
        a0 += w0 * bf2f(v0.x) + w1 * bf2f(v1.x) + w2 * bf2f(v2.x) + w3 * bf2f(v3.x);
        a1 += w0 * bf2f(v0.y) + w1 * bf2f(v1.y) + w2 * bf2f(v2.y) + w3 * bf2f(v3.y);
        a2 += w0 * bf2f(v0.z) + w1 * bf2f(v1.z) + w2 * bf2f(v2.z) + w3 * bf2f(v3.z);
        a3 += w0 * bf2f(v0.w) + w1 * bf2f(v1.w) + w2 * bf2f(v2.w) + w3 * bf2f(v3.w);
    }
    for (; j < end; j++) {
        int s0 = csr[j];
        float w0 = edgew(as[s0 * 4 + head] + adv);
        ushort4 v0 = *(const ushort4*)(h1b + (size_t)s0 * 256 + coff);
        ssum += w0;
        a0 += w0 * bf2f(v0.x); a1 += w0 * bf2f(v0.y);
        a2 += w0 * bf2f(v0.z); a3 += w0 * bf2f(v0.w);
    }
    float inv = 1.f / ssum;
    float o0 = a0 * inv + b1[coff + 0];
    float o1 = a1 * inv + b1[coff + 1];
    float o2 = a2 * inv + b1[coff + 2];
    float o3 = a3 * inv + b1[coff + 3];
    float4 o;
    o.x = o0 > 0.f ? o0 : 0.f; o.y = o1 > 0.f ? o1 : 0.f;
    o.z = o2 > 0.f ? o2 : 0.f; o.w = o3 > 0.f ? o3 : 0.f;
    *(float4*)(out1 + (size_t)n * 256 + coff) = o;
}

__global__ __launch_bounds__(256) void k_agg2(const ushort* __restrict__ h2b,
                                              const float* __restrict__ as, const float* __restrict__ ad,
                                              const int* __restrict__ rowstart, const int* __restrict__ csr,
                                              const float* __restrict__ b2,
                                              float* __restrict__ out2, int N) {
    int n = blockIdx.x * 4 + (threadIdx.x >> 6);
    int lane = threadIdx.x & 63;
    if (n >= N) return;
    float adv = ad[n];
    int beg = rowstart[n], end = rowstart[n + 1];
    float acc = 0.f, ssum = 0.f;
    int j = beg;
    for (; j + 4 <= end; j += 4) {
        int s0 = csr[j + 0], s1 = csr[j + 1], s2 = csr[j + 2], s3 = csr[j + 3];
        float e0 = as[s0], e1 = as[s1], e2 = as[s2], e3 = as[s3];
        ushort v0 = h2b[(size_t)s0 * 64 + lane];
        ushort v1 = h2b[(size_t)s1 * 64 + lane];
        ushort v2 = h2b[(size_t)s2 * 64 + lane];
        ushort v3 = h2b[(size_t)s3 * 64 + lane];
        float w0 = edgew(e0 + adv), w1 = edgew(e1 + adv);
        float w2 = edgew(e2 + adv), w3 = edgew(e3 + adv);
        ssum += (w0 + w1) + (w2 + w3);
        acc += w0 * bf2f(v0) + w1 * bf2f(v1) + w2 * bf2f(v2) + w3 * bf2f(v3);
    }
    for (; j < end; j++) {
        int s0 = csr[j];
        float w0 = edgew(as[s0] + adv);
        ssum += w0;
        acc += w0 * bf2f(h2b[(size_t)s0 * 64 + lane]);
    }
    float o = acc / ssum + b2[lane];
    out2[(size_t)n * 64 + lane] = o > 0.f ? o : 0.f;
}

// ---------------------------------------------------------------- pool + final linear

__global__ __launch_bounds__(64) void k_pool(const float* __restrict__ out2,
                                             const int* __restrict__ gstart,
                                             const float* __restrict__ lin_w,
                                             const float* __restrict__ lin_b,
                                             float* __restrict__ out, int NG) {
    __shared__ float mean[64];
    int g = blockIdx.x;
    int lane = threadIdx.x;
    int beg = gstart[g], end = gstart[g + 1];
    float s = 0.f;
    for (int n = beg; n < end; n++) s += out2[(size_t)n * 64 + lane];
    float cnt = (float)(end - beg);
    mean[lane] = s / fmaxf(cnt, 1.f);
    __syncthreads();
    if (lane < NC) {
        float acc = lin_b[lane];
        #pragma unroll
        for (int c = 0; c < 64; c++) acc += mean[c] * lin_w[c * NC + lane];
        out[g * NC + lane] = acc;
    }
}

// ---------------------------------------------------------------- launch

extern "C" void kernel_launch(void* const* d_in, const int* in_sizes, int n_in,
                              void* d_out, int out_size, void* d_ws, size_t ws_size,
                              hipStream_t stream) {
    const float* x      = (const float*)d_in[0];
    const int*   ei     = (const int*)d_in[1];
    const int*   batch  = (const int*)d_in[2];
    const float* W1     = (const float*)d_in[3];
    const float* att_s1 = (const float*)d_in[4];
    const float* att_d1 = (const float*)d_in[5];
    const float* b1     = (const float*)d_in[6];
    const float* W2     = (const float*)d_in[7];
    const float* att_s2 = (const float*)d_in[8];
    const float* att_d2 = (const float*)d_in[9];
    const float* b2     = (const float*)d_in[10];
    const float* lin_w  = (const float*)d_in[11];
    const float* lin_b  = (const float*)d_in[12];
    float* out = (float*)d_out;

    const int N  = in_sizes[0] / F_IN;   // 50000
    const int E  = in_sizes[1] / 2;      // 800000
    const int NG = out_size / NC;        // 512
    const int NE = E + N;
    const int NB = (N + 1023) / 1024;    // scan blocks

    char* p = (char*)d_ws;
    auto alloc = [&](size_t bytes) { char* r = p; p += (bytes + 255) & ~(size_t)255; return r; };
    ushort* h1b     = (ushort*)alloc(sizeof(ushort) * (size_t)N * 256);
    float*  out1    = (float*)alloc(sizeof(float) * (size_t)N * 256);
    ushort* h2b     = (ushort*)alloc(sizeof(ushort) * (size_t)N * 64);
    float*  out2    = (float*)alloc(sizeof(float) * (size_t)N * 64);
    float*  as1     = (float*)alloc(sizeof(float) * (size_t)N * 4);
    float*  ad1     = (float*)alloc(sizeof(float) * (size_t)N * 4);
    float*  as2     = (float*)alloc(sizeof(float) * (size_t)N);
    float*  ad2     = (float*)alloc(sizeof(float) * (size_t)N);
    int*    rowstart= (int*)alloc(sizeof(int) * (size_t)(N + 1));
    int*    itmp    = (int*)alloc(sizeof(int) * (size_t)N);      // deg, then cursor
    int*    csr     = (int*)alloc(sizeof(int) * (size_t)NE);
    int*    counts  = (int*)alloc(sizeof(int) * (size_t)NG);
    int*    gstart  = (int*)alloc(sizeof(int) * (size_t)(NG + 1));
    int*    bsum    = (int*)alloc(sizeof(int) * 1024);
    int*    boff    = (int*)alloc(sizeof(int) * 1024);

    int bs = 256;
    // CSR build + batch counts
    k_init<<<(N + bs - 1) / bs, bs, 0, stream>>>(itmp, N, counts, NG);
    k_count<<<(E + bs - 1) / bs, bs, 0, stream>>>(ei, E, itmp, batch, N, counts);
    k_scan_part<<<NB, 1024, 0, stream>>>(itmp, rowstart, bsum, N);
    k_scan_bsum<<<1, 1024, 0, stream>>>(bsum, boff, NB, rowstart + N);
    k_scan_add_self<<<(N + 1023) / 1024, 1024, 0, stream>>>(rowstart, boff, itmp, csr, N);
    k_scan<<<1, 1024, 0, stream>>>(counts, gstart, NG);
    k_scatter<<<(E + bs - 1) / bs, bs, 0, stream>>>(ei, E, rowstart, itmp, csr);

    // layer 1 (GEMM + fused att coefs), then aggregate
    k_gemm1<<<(N + 31) / 32, 256, 0, stream>>>(x, W1, att_s1, att_d1, h1b, as1, ad1, N);
    k_agg1<<<(N + 3) / 4, 256, 0, stream>>>(h1b, as1, ad1, rowstart, csr, b1, out1, N);

    // layer 2
    k_gemm2<<<(N + 127) / 128, 256, 0, stream>>>(out1, W2, att_s2, att_d2, h2b, as2, ad2, N);
    k_agg2<<<(N + 3) / 4, 256, 0, stream>>>(h2b, as2, ad2, rowstart, csr, b2, out2, N);

    // pool + linear
    k_pool<<<NG, 64, 0, stream>>>(out2, gstart, lin_w, lin_b, out, NG);
}

// Round 6
// 323.790 us; speedup vs baseline: 1.3881x; 1.3881x over previous
//
#include <hip/hip_runtime.h>

#define F_IN 128
#define HID 64
#define HEADS 4
#define NC 8

typedef __bf16 bf16_t;
typedef bf16_t bf16x8 __attribute__((ext_vector_type(8)));
typedef float f32x4 __attribute__((ext_vector_type(4)));

union BF8 { bf16x8 v; ushort u[8]; };

// ---------------------------------------------------------------- helpers

__device__ __forceinline__ ushort f2bf(float f) {      // RNE round to bf16
    uint u = __float_as_uint(f);
    return (ushort)((u + 0x7fffu + ((u >> 16) & 1u)) >> 16);
}
__device__ __forceinline__ float bf2f(ushort h) {
    return __uint_as_float(((uint)h) << 16);
}
__device__ __forceinline__ float edgew(float e) {      // exp(leaky_relu(e, 0.2))
    e = (e > 0.f) ? e : 0.2f * e;
    return __expf(e);
}

// ---------------------------------------------------------------- init / CSR

__global__ void k_init(int* __restrict__ deg, int N, int* __restrict__ counts, int NG) {
    int i = blockIdx.x * blockDim.x + threadIdx.x;
    if (i < N) deg[i] = 1;              // self loop contributes 1
    if (i < NG) counts[i] = 0;
}

// fused: edge degree count + batch count (grid covers max(E,N))
__global__ void k_count(const int* __restrict__ ei, int E, int* __restrict__ deg,
                        const int* __restrict__ batch, int N, int* __restrict__ counts) {
    int i = blockIdx.x * blockDim.x + threadIdx.x;
    if (i < E) atomicAdd(&deg[ei[E + i]], 1);   // dst row
    if (i < N) atomicAdd(&counts[batch[i]], 1);
}

// hierarchical scan: part (per 1024-block excl + block total), bsum scan, add
__global__ __launch_bounds__(1024) void k_scan_part(const int* __restrict__ v,
                                                    int* __restrict__ excl,
                                                    int* __restrict__ bsum, int n) {
    __shared__ int buf[1024];
    int tid = threadIdx.x;
    int i = blockIdx.x * 1024 + tid;
    int val = (i < n) ? v[i] : 0;
    buf[tid] = val;
    __syncthreads();
    for (int off = 1; off < 1024; off <<= 1) {
        int t = (tid >= off) ? buf[tid - off] : 0;
        __syncthreads();
        buf[tid] += t;
        __syncthreads();
    }
    if (i < n) excl[i] = buf[tid] - val;
    if (tid == 1023) bsum[blockIdx.x] = buf[1023];
}

__global__ __launch_bounds__(1024) void k_scan_bsum(const int* __restrict__ bsum,
                                                    int* __restrict__ boff, int nb,
                                                    int* __restrict__ total_out) {
    __shared__ int buf[1024];
    int tid = threadIdx.x;
    int val = (tid < nb) ? bsum[tid] : 0;
    buf[tid] = val;
    __syncthreads();
    for (int off = 1; off < 1024; off <<= 1) {
        int t = (tid >= off) ? buf[tid - off] : 0;
        __syncthreads();
        buf[tid] += t;
        __syncthreads();
    }
    if (tid < nb) boff[tid] = buf[tid] - val;
    if (tid == 1023) total_out[0] = buf[1023];
}

// finalize rowstart (+= block offset) AND seed csr with self-loop + cursor=1
__global__ void k_scan_add_self(int* __restrict__ rowstart, const int* __restrict__ boff,
                                int* __restrict__ cursor, int* __restrict__ csr, int n) {
    int i = blockIdx.x * blockDim.x + threadIdx.x;
    if (i < n) {
        int rs = rowstart[i] + boff[i >> 10];
        rowstart[i] = rs;
        csr[rs] = i;          // self loop first
        cursor[i] = 1;
    }
}

// single-block scan for small arrays (NG=512); writes excl[0..n]
__global__ __launch_bounds__(1024) void k_scan(const int* __restrict__ v, int* __restrict__ excl, int n) {
    __shared__ int buf[1024];
    int tid = threadIdx.x;
    int val = (tid < n) ? v[tid] : 0;
    buf[tid] = val;
    __syncthreads();
    for (int off = 1; off < 1024; off <<= 1) {
        int t = (tid >= off) ? buf[tid - off] : 0;
        __syncthreads();
        buf[tid] += t;
        __syncthreads();
    }
    if (tid < n) excl[tid] = buf[tid] - val;
    if (tid == 1023) excl[n] = buf[1023];
}

__global__ void k_scatter(const int* __restrict__ ei, int E, const int* __restrict__ rowstart,
                          int* __restrict__ cursor, int* __restrict__ csr) {
    int e = blockIdx.x * blockDim.x + threadIdx.x;
    if (e < E) {
        int d = ei[E + e], s = ei[e];
        int pos = atomicAdd(&cursor[d], 1);
        csr[rowstart[d] + pos] = s;
    }
}

// ---------------------------------------------------------------- W pack (bf16 hi/lo, MFMA B-fragment order)
// W1 pack: [cy(2)][ct(8)][kc(4)][lane(64)][j(8)]  (B[k][n]: k=kc*32+(lane>>4)*8+j, n=cy*128+ct*16+(lane&15))
// W2 pack: [ct(4)][kc(8)][lane(64)][j(8)]
__global__ void k_pack(const float* __restrict__ W1, const float* __restrict__ W2,
                       ushort* __restrict__ w1hi, ushort* __restrict__ w1lo,
                       ushort* __restrict__ w2hi, ushort* __restrict__ w2lo) {
    int i = blockIdx.x * blockDim.x + threadIdx.x;
    if (i < 128 * 256) {
        int k = i >> 8, n = i & 255;
        int cy = n >> 7, ct = (n >> 4) & 7, c = n & 15, kc = k >> 5, ls = (k >> 3) & 3, j = k & 7;
        size_t off = ((((size_t)cy * 8 + ct) * 4 + kc) * 64 + (ls * 16 + c)) * 8 + j;
        float w = W1[i];
        ushort hi = f2bf(w);
        w1hi[off] = hi; w1lo[off] = f2bf(w - bf2f(hi));
    }
    if (i < 256 * 64) {
        int k = i >> 6, n = i & 63;
        int ct = n >> 4, c = n & 15, kc = k >> 5, ls = (k >> 3) & 3, j = k & 7;
        size_t off = (((size_t)ct * 8 + kc) * 64 + (ls * 16 + c)) * 8 + j;
        float w = W2[i];
        ushort hi = f2bf(w);
        w2hi[off] = hi; w2lo[off] = f2bf(w - bf2f(hi));
    }
}

// ---------------------------------------------------------------- layer-1 GEMM (MFMA) + fused att
// h1 = x[N][128] @ W1[128][256], 3-term bf16 split (fp32-equivalent accuracy).
// Block: 256 rows x 128 cols (blockIdx.y = col half). Wave: 64 rows. 4 m-tiles x 8 ct x 4 kc.
__global__ __launch_bounds__(256) void k_gemm1(const float* __restrict__ x,
                                               const ushort* __restrict__ w1hi,
                                               const ushort* __restrict__ w1lo,
                                               const float* __restrict__ atts,
                                               const float* __restrict__ attd,
                                               ushort* __restrict__ h1b,
                                               float* __restrict__ as1, float* __restrict__ ad1,
                                               int N) {
    __shared__ __align__(16) ushort lhi[16384];   // 32 KB
    __shared__ __align__(16) ushort llo[16384];   // 32 KB
    int tid = threadIdx.x;
    int cy = blockIdx.y;
    {   // stage this col-half's W pack slice (hi+lo)
        float4* dh = (float4*)lhi; const float4* sh = (const float4*)(w1hi + (size_t)cy * 16384);
        float4* dl = (float4*)llo; const float4* sl = (const float4*)(w1lo + (size_t)cy * 16384);
        #pragma unroll
        for (int i = 0; i < 8; i++) {
            dh[tid + i * 256] = sh[tid + i * 256];
            dl[tid + i * 256] = sl[tid + i * 256];
        }
    }
    __syncthreads();
    int w = tid >> 6, l = tid & 63;
    int lc = l & 15, lk = l >> 4;
    int rbase = blockIdx.x * 256 + w * 64;

    f32x4 acc[4][8];
    #pragma unroll
    for (int mt = 0; mt < 4; mt++)
        #pragma unroll
        for (int ct = 0; ct < 8; ct++) acc[mt][ct] = (f32x4){0.f, 0.f, 0.f, 0.f};

    #pragma unroll
    for (int kc = 0; kc < 4; kc++) {
        BF8 ahi[4], alo[4];
        #pragma unroll
        for (int mt = 0; mt < 4; mt++) {
            int row = rbase + mt * 16 + lc;
            float4 v0 = {0.f, 0.f, 0.f, 0.f}, v1 = v0;
            if (row < N) {
                const float* xp = x + (size_t)row * F_IN + kc * 32 + lk * 8;
                v0 = *(const float4*)xp; v1 = *(const float4*)(xp + 4);
            }
            float vals[8] = {v0.x, v0.y, v0.z, v0.w, v1.x, v1.y, v1.z, v1.w};
            #pragma unroll
            for (int j = 0; j < 8; j++) {
                ushort h = f2bf(vals[j]);
                ahi[mt].u[j] = h;
                alo[mt].u[j] = f2bf(vals[j] - bf2f(h));
            }
        }
        #pragma unroll
        for (int ct = 0; ct < 8; ct++) {
            int boff = ((ct * 4 + kc) * 64 + l) * 8;
            bf16x8 bhi = *(const bf16x8*)(lhi + boff);
            bf16x8 blo = *(const bf16x8*)(llo + boff);
            #pragma unroll
            for (int mt = 0; mt < 4; mt++) {
                acc[mt][ct] = __builtin_amdgcn_mfma_f32_16x16x32_bf16(ahi[mt].v, bhi, acc[mt][ct], 0, 0, 0);
                acc[mt][ct] = __builtin_amdgcn_mfma_f32_16x16x32_bf16(alo[mt].v, bhi, acc[mt][ct], 0, 0, 0);
                acc[mt][ct] = __builtin_amdgcn_mfma_f32_16x16x32_bf16(ahi[mt].v, blo, acc[mt][ct], 0, 0, 0);
            }
        }
    }
    // epilogue: C/D layout col=lane&15, row=(lane>>4)*4+reg
    #pragma unroll
    for (int mt = 0; mt < 4; mt++) {
        int rowb = rbase + mt * 16 + lk * 4;
        #pragma unroll
        for (int ct = 0; ct < 8; ct++) {
            int col = cy * 128 + ct * 16 + lc;
            #pragma unroll
            for (int r = 0; r < 4; r++) {
                int row = rowb + r;
                if (row < N) h1b[(size_t)row * 256 + col] = f2bf(acc[mt][ct][r]);
            }
        }
        #pragma unroll
        for (int hh = 0; hh < 2; hh++) {
            float s[4] = {0.f, 0.f, 0.f, 0.f}, d[4] = {0.f, 0.f, 0.f, 0.f};
            #pragma unroll
            for (int cq = 0; cq < 4; cq++) {
                int ct = hh * 4 + cq;
                int col = cy * 128 + ct * 16 + lc;
                float av = atts[col], dv = attd[col];
                #pragma unroll
                for (int r = 0; r < 4; r++) { s[r] += acc[mt][ct][r] * av; d[r] += acc[mt][ct][r] * dv; }
            }
            #pragma unroll
            for (int r = 0; r < 4; r++) {
                #pragma unroll
                for (int off = 1; off < 16; off <<= 1) {
                    s[r] += __shfl_xor(s[r], off);
                    d[r] += __shfl_xor(d[r], off);
                }
            }
            if (lc == 0) {
                int head = cy * 2 + hh;
                #pragma unroll
                for (int r = 0; r < 4; r++) {
                    int row = rowb + r;
                    if (row < N) { as1[row * 4 + head] = s[r]; ad1[row * 4 + head] = d[r]; }
                }
            }
        }
    }
}

// ---------------------------------------------------------------- layer-2 GEMM (MFMA) + fused att
// h2 = out1[N][256] @ W2[256][64]. Block: 256 rows x 64 cols. Wave: 64 rows. 4 mt x 4 ct x 8 kc.
__global__ __launch_bounds__(256) void k_gemm2(const float* __restrict__ xin,
                                               const ushort* __restrict__ w2hi,
                                               const ushort* __restrict__ w2lo,
                                               const float* __restrict__ atts,
                                               const float* __restrict__ attd,
                                               ushort* __restrict__ h2b,
                                               float* __restrict__ as2, float* __restrict__ ad2,
                                               int N) {
    __shared__ __align__(16) ushort lhi[16384];
    __shared__ __align__(16) ushort llo[16384];
    int tid = threadIdx.x;
    {
        float4* dh = (float4*)lhi; const float4* sh = (const float4*)w2hi;
        float4* dl = (float4*)llo; const float4* sl = (const float4*)w2lo;
        #pragma unroll
        for (int i = 0; i < 8; i++) {
            dh[tid + i * 256] = sh[tid + i * 256];
            dl[tid + i * 256] = sl[tid + i * 256];
        }
    }
    __syncthreads();
    int w = tid >> 6, l = tid & 63;
    int lc = l & 15, lk = l >> 4;
    int rbase = blockIdx.x * 256 + w * 64;

    f32x4 acc[4][4];
    #pragma unroll
    for (int mt = 0; mt < 4; mt++)
        #pragma unroll
        for (int ct = 0; ct < 4; ct++) acc[mt][ct] = (f32x4){0.f, 0.f, 0.f, 0.f};

    #pragma unroll
    for (int kc = 0; kc < 8; kc++) {
        BF8 ahi[4], alo[4];
        #pragma unroll
        for (int mt = 0; mt < 4; mt++) {
            int row = rbase + mt * 16 + lc;
            float4 v0 = {0.f, 0.f, 0.f, 0.f}, v1 = v0;
            if (row < N) {
                const float* xp = xin + (size_t)row * 256 + kc * 32 + lk * 8;
                v0 = *(const float4*)xp; v1 = *(const float4*)(xp + 4);
            }
            float vals[8] = {v0.x, v0.y, v0.z, v0.w, v1.x, v1.y, v1.z, v1.w};
            #pragma unroll
            for (int j = 0; j < 8; j++) {
                ushort h = f2bf(vals[j]);
                ahi[mt].u[j] = h;
                alo[mt].u[j] = f2bf(vals[j] - bf2f(h));
            }
        }
        #pragma unroll
        for (int ct = 0; ct < 4; ct++) {
            int boff = ((ct * 8 + kc) * 64 + l) * 8;
            bf16x8 bhi = *(const bf16x8*)(lhi + boff);
            bf16x8 blo = *(const bf16x8*)(llo + boff);
            #pragma unroll
            for (int mt = 0; mt < 4; mt++) {
                acc[mt][ct] = __builtin_amdgcn_mfma_f32_16x16x32_bf16(ahi[mt].v, bhi, acc[mt][ct], 0, 0, 0);
                acc[mt][ct] = __builtin_amdgcn_mfma_f32_16x16x32_bf16(alo[mt].v, bhi, acc[mt][ct], 0, 0, 0);
                acc[mt][ct] = __builtin_amdgcn_mfma_f32_16x16x32_bf16(ahi[mt].v, blo, acc[mt][ct], 0, 0, 0);
            }
        }
    }
    #pragma unroll
    for (int mt = 0; mt < 4; mt++) {
        int rowb = rbase + mt * 16 + lk * 4;
        #pragma unroll
        for (int ct = 0; ct < 4; ct++) {
            int col = ct * 16 + lc;
            #pragma unroll
            for (int r = 0; r < 4; r++) {
                int row = rowb + r;
                if (row < N) h2b[(size_t)row * 64 + col] = f2bf(acc[mt][ct][r]);
            }
        }
        float s[4] = {0.f, 0.f, 0.f, 0.f}, d[4] = {0.f, 0.f, 0.f, 0.f};
        #pragma unroll
        for (int ct = 0; ct < 4; ct++) {
            int col = ct * 16 + lc;
            float av = atts[col], dv = attd[col];
            #pragma unroll
            for (int r = 0; r < 4; r++) { s[r] += acc[mt][ct][r] * av; d[r] += acc[mt][ct][r] * dv; }
        }
        #pragma unroll
        for (int r = 0; r < 4; r++) {
            #pragma unroll
            for (int off = 1; off < 16; off <<= 1) {
                s[r] += __shfl_xor(s[r], off);
                d[r] += __shfl_xor(d[r], off);
            }
        }
        if (lc == 0) {
            #pragma unroll
            for (int r = 0; r < 4; r++) {
                int row = rowb + r;
                if (row < N) { as2[row] = s[r]; ad2[row] = d[r]; }
            }
        }
    }
}

// ---------------------------------------------------------------- aggregation (1 wave / node)

__global__ __launch_bounds__(256) void k_agg1(const ushort* __restrict__ h1b,
                                              const float* __restrict__ as, const float* __restrict__ ad,
                                              const int* __restrict__ rowstart, const int* __restrict__ csr,
                                              const float* __restrict__ b1,
                                              float* __restrict__ out1, int N) {
    int n = blockIdx.x * 4 + (threadIdx.x >> 6);
    int lane = threadIdx.x & 63;
    if (n >= N) return;
    int head = lane >> 4;
    int coff = lane * 4;
    float adv = ad[n * 4 + head];
    int beg = rowstart[n], end = rowstart[n + 1];
    float a0 = 0.f, a1 = 0.f, a2 = 0.f, a3 = 0.f, ssum = 0.f;
    int j = beg;
    for (; j + 4 <= end; j += 4) {
        int s0 = csr[j + 0], s1 = csr[j + 1], s2 = csr[j + 2], s3 = csr[j + 3];
        float e0 = as[s0 * 4 + head], e1 = as[s1 * 4 + head];
        float e2 = as[s2 * 4 + head], e3 = as[s3 * 4 + head];
        ushort4 v0 = *(const ushort4*)(h1b + (size_t)s0 * 256 + coff);
        ushort4 v1 = *(const ushort4*)(h1b + (size_t)s1 * 256 + coff);
        ushort4 v2 = *(const ushort4*)(h1b + (size_t)s2 * 256 + coff);
        ushort4 v3 = *(const ushort4*)(h1b + (size_t)s3 * 256 + coff);
        float w0 = edgew(e0 + adv), w1 = edgew(e1 + adv);
        float w2 = edgew(e2 + adv), w3 = edgew(e3 + adv);
        ssum += (w0 + w1) + (w2 + w3);
        a0 += w0 * bf2f(v0.x) + w1 * bf2f(v1.x) + w2 * bf2f(v2.x) + w3 * bf2f(v3.x);
        a1 += w0 * bf2f(v0.y) + w1 * bf2f(v1.y) + w2 * bf2f(v2.y) + w3 * bf2f(v3.y);
        a2 += w0 * bf2f(v0.z) + w1 * bf2f(v1.z) + w2 * bf2f(v2.z) + w3 * bf2f(v3.z);
        a3 += w0 * bf2f(v0.w) + w1 * bf2f(v1.w) + w2 * bf2f(v2.w) + w3 * bf2f(v3.w);
    }
    for (; j < end; j++) {
        int s0 = csr[j];
        float w0 = edgew(as[s0 * 4 + head] + adv);
        ushort4 v0 = *(const ushort4*)(h1b + (size_t)s0 * 256 + coff);
        ssum += w0;
        a0 += w0 * bf2f(v0.x); a1 += w0 * bf2f(v0.y);
        a2 += w0 * bf2f(v0.z); a3 += w0 * bf2f(v0.w);
    }
    float inv = 1.f / ssum;
    float o0 = a0 * inv + b1[coff + 0];
    float o1 = a1 * inv + b1[coff + 1];
    float o2 = a2 * inv + b1[coff + 2];
    float o3 = a3 * inv + b1[coff + 3];
    float4 o;
    o.x = o0 > 0.f ? o0 : 0.f; o.y = o1 > 0.f ? o1 : 0.f;
    o.z = o2 > 0.f ? o2 : 0.f; o.w = o3 > 0.f ? o3 : 0.f;
    *(float4*)(out1 + (size_t)n * 256 + coff) = o;
}

__global__ __launch_bounds__(256) void k_agg2(const ushort* __restrict__ h2b,
                                              const float* __restrict__ as, const float* __restrict__ ad,
                                              const int* __restrict__ rowstart, const int* __restrict__ csr,
                                              const float* __restrict__ b2,
                                              float* __restrict__ out2, int N) {
    int n = blockIdx.x * 4 + (threadIdx.x >> 6);
    int lane = threadIdx.x & 63;
    if (n >= N) return;
    float adv = ad[n];
    int beg = rowstart[n], end = rowstart[n + 1];
    float acc = 0.f, ssum = 0.f;
    int j = beg;
    for (; j + 4 <= end; j += 4) {
        int s0 = csr[j + 0], s1 = csr[j + 1], s2 = csr[j + 2], s3 = csr[j + 3];
        float e0 = as[s0], e1 = as[s1], e2 = as[s2], e3 = as[s3];
        ushort v0 = h2b[(size_t)s0 * 64 + lane];
        ushort v1 = h2b[(size_t)s1 * 64 + lane];
        ushort v2 = h2b[(size_t)s2 * 64 + lane];
        ushort v3 = h2b[(size_t)s3 * 64 + lane];
        float w0 = edgew(e0 + adv), w1 = edgew(e1 + adv);
        float w2 = edgew(e2 + adv), w3 = edgew(e3 + adv);
        ssum += (w0 + w1) + (w2 + w3);
        acc += w0 * bf2f(v0) + w1 * bf2f(v1) + w2 * bf2f(v2) + w3 * bf2f(v3);
    }
    for (; j < end; j++) {
        int s0 = csr[j];
        float w0 = edgew(as[s0] + adv);
        ssum += w0;
        acc += w0 * bf2f(h2b[(size_t)s0 * 64 + lane]);
    }
    float o = acc / ssum + b2[lane];
    out2[(size_t)n * 64 + lane] = o > 0.f ? o : 0.f;
}

// ---------------------------------------------------------------- pool + final linear

__global__ __launch_bounds__(64) void k_pool(const float* __restrict__ out2,
                                             const int* __restrict__ gstart,
                                             const float* __restrict__ lin_w,
                                             const float* __restrict__ lin_b,
                                             float* __restrict__ out, int NG) {
    __shared__ float mean[64];
    int g = blockIdx.x;
    int lane = threadIdx.x;
    int beg = gstart[g], end = gstart[g + 1];
    float s = 0.f;
    for (int n = beg; n < end; n++) s += out2[(size_t)n * 64 + lane];
    float cnt = (float)(end - beg);
    mean[lane] = s / fmaxf(cnt, 1.f);
    __syncthreads();
    if (lane < NC) {
        float acc = lin_b[lane];
        #pragma unroll
        for (int c = 0; c < 64; c++) acc += mean[c] * lin_w[c * NC + lane];
        out[g * NC + lane] = acc;
    }
}

// ---------------------------------------------------------------- launch

extern "C" void kernel_launch(void* const* d_in, const int* in_sizes, int n_in,
                              void* d_out, int out_size, void* d_ws, size_t ws_size,
                              hipStream_t stream) {
    const float* x      = (const float*)d_in[0];
    const int*   ei     = (const int*)d_in[1];
    const int*   batch  = (const int*)d_in[2];
    const float* W1     = (const float*)d_in[3];
    const float* att_s1 = (const float*)d_in[4];
    const float* att_d1 = (const float*)d_in[5];
    const float* b1     = (const float*)d_in[6];
    const float* W2     = (const float*)d_in[7];
    const float* att_s2 = (const float*)d_in[8];
    const float* att_d2 = (const float*)d_in[9];
    const float* b2     = (const float*)d_in[10];
    const float* lin_w  = (const float*)d_in[11];
    const float* lin_b  = (const float*)d_in[12];
    float* out = (float*)d_out;

    const int N  = in_sizes[0] / F_IN;   // 50000
    const int E  = in_sizes[1] / 2;      // 800000
    const int NG = out_size / NC;        // 512
    const int NE = E + N;
    const int NB = (N + 1023) / 1024;    // scan blocks

    char* p = (char*)d_ws;
    auto alloc = [&](size_t bytes) { char* r = p; p += (bytes + 255) & ~(size_t)255; return r; };
    ushort* h1b     = (ushort*)alloc(sizeof(ushort) * (size_t)N * 256);
    float*  out1    = (float*)alloc(sizeof(float) * (size_t)N * 256);
    ushort* h2b     = (ushort*)alloc(sizeof(ushort) * (size_t)N * 64);
    float*  out2    = (float*)alloc(sizeof(float) * (size_t)N * 64);
    float*  as1     = (float*)alloc(sizeof(float) * (size_t)N * 4);
    float*  ad1     = (float*)alloc(sizeof(float) * (size_t)N * 4);
    float*  as2     = (float*)alloc(sizeof(float) * (size_t)N);
    float*  ad2     = (float*)alloc(sizeof(float) * (size_t)N);
    int*    rowstart= (int*)alloc(sizeof(int) * (size_t)(N + 1));
    int*    itmp    = (int*)alloc(sizeof(int) * (size_t)N);      // deg, then cursor
    int*    csr     = (int*)alloc(sizeof(int) * (size_t)NE);
    int*    counts  = (int*)alloc(sizeof(int) * (size_t)NG);
    int*    gstart  = (int*)alloc(sizeof(int) * (size_t)(NG + 1));
    int*    bsum    = (int*)alloc(sizeof(int) * 1024);
    int*    boff    = (int*)alloc(sizeof(int) * 1024);
    ushort* w1hi    = (ushort*)alloc(sizeof(ushort) * 32768);
    ushort* w1lo    = (ushort*)alloc(sizeof(ushort) * 32768);
    ushort* w2hi    = (ushort*)alloc(sizeof(ushort) * 16384);
    ushort* w2lo    = (ushort*)alloc(sizeof(ushort) * 16384);

    int bs = 256;
    // weight packing (independent of CSR chain)
    k_pack<<<128, 256, 0, stream>>>(W1, W2, w1hi, w1lo, w2hi, w2lo);
    // CSR build + batch counts
    k_init<<<(N + bs - 1) / bs, bs, 0, stream>>>(itmp, N, counts, NG);
    k_count<<<(E + bs - 1) / bs, bs, 0, stream>>>(ei, E, itmp, batch, N, counts);
    k_scan_part<<<NB, 1024, 0, stream>>>(itmp, rowstart, bsum, N);
    k_scan_bsum<<<1, 1024, 0, stream>>>(bsum, boff, NB, rowstart + N);
    k_scan_add_self<<<(N + 1023) / 1024, 1024, 0, stream>>>(rowstart, boff, itmp, csr, N);
    k_scan<<<1, 1024, 0, stream>>>(counts, gstart, NG);
    k_scatter<<<(E + bs - 1) / bs, bs, 0, stream>>>(ei, E, rowstart, itmp, csr);

    // layer 1 (MFMA GEMM + fused att coefs), then aggregate
    k_gemm1<<<dim3((N + 255) / 256, 2), 256, 0, stream>>>(x, w1hi, w1lo, att_s1, att_d1, h1b, as1, ad1, N);
    k_agg1<<<(N + 3) / 4, 256, 0, stream>>>(h1b, as1, ad1, rowstart, csr, b1, out1, N);

    // layer 2
    k_gemm2<<<(N + 255) / 256, 256, 0, stream>>>(out1, w2hi, w2lo, att_s2, att_d2, h2b, as2, ad2, N);
    k_agg2<<<(N + 3) / 4, 256, 0, stream>>>(h2b, as2, ad2, rowstart, csr, b2, out2, N);

    // pool + linear
    k_pool<<<NG, 64, 0, stream>>>(out2, gstart, lin_w, lin_b, out, NG);
}

// Round 7
// 321.382 us; speedup vs baseline: 1.3985x; 1.0075x over previous
//
#include <hip/hip_runtime.h>

#define F_IN 128
#define HID 64
#define HEADS 4
#define NC 8

typedef __bf16 bf16_t;
typedef bf16_t bf16x8 __attribute__((ext_vector_type(8)));
typedef float f32x4 __attribute__((ext_vector_type(4)));

union BF8 { bf16x8 v; ushort u[8]; };

// ---------------------------------------------------------------- helpers

__device__ __forceinline__ ushort f2bf(float f) {      // RNE round to bf16
    uint u = __float_as_uint(f);
    return (ushort)((u + 0x7fffu + ((u >> 16) & 1u)) >> 16);
}
__device__ __forceinline__ float bf2f(ushort h) {
    return __uint_as_float(((uint)h) << 16);
}
__device__ __forceinline__ float edgew(float e) {      // exp(leaky_relu(e, 0.2))
    e = (e > 0.f) ? e : 0.2f * e;
    return __expf(e);
}

// ---------------------------------------------------------------- setup: W pack + deg/count init
// W1 pack: [cy(2)][ct(8)][kc(4)][lane(64)][j(8)]  (B[k][n]: k=kc*32+(lane>>4)*8+j, n=cy*128+ct*16+(lane&15))
// W2 pack: [ct(4)][kc(8)][lane(64)][j(8)]
__global__ void k_setup(const float* __restrict__ W1, const float* __restrict__ W2,
                        ushort* __restrict__ w1hi, ushort* __restrict__ w1lo,
                        ushort* __restrict__ w2hi, ushort* __restrict__ w2lo,
                        int* __restrict__ deg, int N, int* __restrict__ counts, int NG) {
    int i = blockIdx.x * blockDim.x + threadIdx.x;
    if (i < N) deg[i] = 1;              // self loop contributes 1
    if (i < NG) counts[i] = 0;
    if (i < 128 * 256) {
        int k = i >> 8, n = i & 255;
        int cy = n >> 7, ct = (n >> 4) & 7, c = n & 15, kc = k >> 5, ls = (k >> 3) & 3, j = k & 7;
        size_t off = ((((size_t)cy * 8 + ct) * 4 + kc) * 64 + (ls * 16 + c)) * 8 + j;
        float w = W1[i];
        ushort hi = f2bf(w);
        w1hi[off] = hi; w1lo[off] = f2bf(w - bf2f(hi));
    }
    if (i < 256 * 64) {
        int k = i >> 6, n = i & 63;
        int ct = n >> 4, c = n & 15, kc = k >> 5, ls = (k >> 3) & 3, j = k & 7;
        size_t off = (((size_t)ct * 8 + kc) * 64 + (ls * 16 + c)) * 8 + j;
        float w = W2[i];
        ushort hi = f2bf(w);
        w2hi[off] = hi; w2lo[off] = f2bf(w - bf2f(hi));
    }
}

// fused: edge degree count + batch count (grid covers max(E,N))
__global__ void k_count(const int* __restrict__ ei, int E, int* __restrict__ deg,
                        const int* __restrict__ batch, int N, int* __restrict__ counts) {
    int i = blockIdx.x * blockDim.x + threadIdx.x;
    if (i < E) atomicAdd(&deg[ei[E + i]], 1);   // dst row
    if (i < N) atomicAdd(&counts[batch[i]], 1);
}

// hierarchical scan: part (per 1024-block excl + block total)
__global__ __launch_bounds__(1024) void k_scan_part(const int* __restrict__ v,
                                                    int* __restrict__ excl,
                                                    int* __restrict__ bsum, int n) {
    __shared__ int buf[1024];
    int tid = threadIdx.x;
    int i = blockIdx.x * 1024 + tid;
    int val = (i < n) ? v[i] : 0;
    buf[tid] = val;
    __syncthreads();
    for (int off = 1; off < 1024; off <<= 1) {
        int t = (tid >= off) ? buf[tid - off] : 0;
        __syncthreads();
        buf[tid] += t;
        __syncthreads();
    }
    if (i < n) excl[i] = buf[tid] - val;
    if (tid == 1023) bsum[blockIdx.x] = buf[1023];
}

// block 0: scan bsum[nb] -> boff (+ total to total_out); block 1: scan counts[ng] -> gstart[0..ng]
__global__ __launch_bounds__(1024) void k_scan_small2(const int* __restrict__ bsum,
                                                      int* __restrict__ boff, int nb,
                                                      int* __restrict__ total_out,
                                                      const int* __restrict__ counts,
                                                      int* __restrict__ gstart, int ng) {
    __shared__ int buf[1024];
    int tid = threadIdx.x;
    const int* src = (blockIdx.x == 0) ? bsum : counts;
    int cnt = (blockIdx.x == 0) ? nb : ng;
    int val = (tid < cnt) ? src[tid] : 0;
    buf[tid] = val;
    __syncthreads();
    for (int off = 1; off < 1024; off <<= 1) {
        int t = (tid >= off) ? buf[tid - off] : 0;
        __syncthreads();
        buf[tid] += t;
        __syncthreads();
    }
    if (blockIdx.x == 0) {
        if (tid < cnt) boff[tid] = buf[tid] - val;
        if (tid == 1023) total_out[0] = buf[1023];
    } else {
        if (tid < cnt) gstart[tid] = buf[tid] - val;
        if (tid == 1023) gstart[ng] = buf[1023];
    }
}

// finalize rowstart (+= block offset) AND seed csr with self-loop + cursor=1
__global__ void k_scan_add_self(int* __restrict__ rowstart, const int* __restrict__ boff,
                                int* __restrict__ cursor, int* __restrict__ csr, int n) {
    int i = blockIdx.x * blockDim.x + threadIdx.x;
    if (i < n) {
        int rs = rowstart[i] + boff[i >> 10];
        rowstart[i] = rs;
        csr[rs] = i;          // self loop first
        cursor[i] = 1;
    }
}

__global__ void k_scatter(const int* __restrict__ ei, int E, const int* __restrict__ rowstart,
                          int* __restrict__ cursor, int* __restrict__ csr) {
    int e = blockIdx.x * blockDim.x + threadIdx.x;
    if (e < E) {
        int d = ei[E + e], s = ei[e];
        int pos = atomicAdd(&cursor[d], 1);
        csr[rowstart[d] + pos] = s;
    }
}

// ---------------------------------------------------------------- layer-1 GEMM (MFMA) + fused att
// h1 = x[N][128] @ W1[128][256], 3-term bf16 split (fp32-equivalent accuracy).
// Block: 256 rows x 128 cols (blockIdx.y = col half). Wave: 64 rows. 4 m-tiles x 8 ct x 4 kc.
__global__ __launch_bounds__(256) void k_gemm1(const float* __restrict__ x,
                                               const ushort* __restrict__ w1hi,
                                               const ushort* __restrict__ w1lo,
                                               const float* __restrict__ atts,
                                               const float* __restrict__ attd,
                                               ushort* __restrict__ h1b,
                                               float* __restrict__ as1, float* __restrict__ ad1,
                                               int N) {
    __shared__ __align__(16) ushort lhi[16384];   // 32 KB
    __shared__ __align__(16) ushort llo[16384];   // 32 KB
    int tid = threadIdx.x;
    int cy = blockIdx.y;
    {   // stage this col-half's W pack slice (hi+lo)
        float4* dh = (float4*)lhi; const float4* sh = (const float4*)(w1hi + (size_t)cy * 16384);
        float4* dl = (float4*)llo; const float4* sl = (const float4*)(w1lo + (size_t)cy * 16384);
        #pragma unroll
        for (int i = 0; i < 8; i++) {
            dh[tid + i * 256] = sh[tid + i * 256];
            dl[tid + i * 256] = sl[tid + i * 256];
        }
    }
    __syncthreads();
    int w = tid >> 6, l = tid & 63;
    int lc = l & 15, lk = l >> 4;
    int rbase = blockIdx.x * 256 + w * 64;

    f32x4 acc[4][8];
    #pragma unroll
    for (int mt = 0; mt < 4; mt++)
        #pragma unroll
        for (int ct = 0; ct < 8; ct++) acc[mt][ct] = (f32x4){0.f, 0.f, 0.f, 0.f};

    #pragma unroll
    for (int kc = 0; kc < 4; kc++) {
        BF8 ahi[4], alo[4];
        #pragma unroll
        for (int mt = 0; mt < 4; mt++) {
            int row = rbase + mt * 16 + lc;
            float4 v0 = {0.f, 0.f, 0.f, 0.f}, v1 = v0;
            if (row < N) {
                const float* xp = x + (size_t)row * F_IN + kc * 32 + lk * 8;
                v0 = *(const float4*)xp; v1 = *(const float4*)(xp + 4);
            }
            float vals[8] = {v0.x, v0.y, v0.z, v0.w, v1.x, v1.y, v1.z, v1.w};
            #pragma unroll
            for (int j = 0; j < 8; j++) {
                ushort h = f2bf(vals[j]);
                ahi[mt].u[j] = h;
                alo[mt].u[j] = f2bf(vals[j] - bf2f(h));
            }
        }
        #pragma unroll
        for (int ct = 0; ct < 8; ct++) {
            int boff = ((ct * 4 + kc) * 64 + l) * 8;
            bf16x8 bhi = *(const bf16x8*)(lhi + boff);
            bf16x8 blo = *(const bf16x8*)(llo + boff);
            #pragma unroll
            for (int mt = 0; mt < 4; mt++) {
                acc[mt][ct] = __builtin_amdgcn_mfma_f32_16x16x32_bf16(ahi[mt].v, bhi, acc[mt][ct], 0, 0, 0);
                acc[mt][ct] = __builtin_amdgcn_mfma_f32_16x16x32_bf16(alo[mt].v, bhi, acc[mt][ct], 0, 0, 0);
                acc[mt][ct] = __builtin_amdgcn_mfma_f32_16x16x32_bf16(ahi[mt].v, blo, acc[mt][ct], 0, 0, 0);
            }
        }
    }
    // epilogue: C/D layout col=lane&15, row=(lane>>4)*4+reg
    #pragma unroll
    for (int mt = 0; mt < 4; mt++) {
        int rowb = rbase + mt * 16 + lk * 4;
        #pragma unroll
        for (int ct = 0; ct < 8; ct++) {
            int col = cy * 128 + ct * 16 + lc;
            #pragma unroll
            for (int r = 0; r < 4; r++) {
                int row = rowb + r;
                if (row < N) h1b[(size_t)row * 256 + col] = f2bf(acc[mt][ct][r]);
            }
        }
        #pragma unroll
        for (int hh = 0; hh < 2; hh++) {
            float s[4] = {0.f, 0.f, 0.f, 0.f}, d[4] = {0.f, 0.f, 0.f, 0.f};
            #pragma unroll
            for (int cq = 0; cq < 4; cq++) {
                int ct = hh * 4 + cq;
                int col = cy * 128 + ct * 16 + lc;
                float av = atts[col], dv = attd[col];
                #pragma unroll
                for (int r = 0; r < 4; r++) { s[r] += acc[mt][ct][r] * av; d[r] += acc[mt][ct][r] * dv; }
            }
            #pragma unroll
            for (int r = 0; r < 4; r++) {
                #pragma unroll
                for (int off = 1; off < 16; off <<= 1) {
                    s[r] += __shfl_xor(s[r], off);
                    d[r] += __shfl_xor(d[r], off);
                }
            }
            if (lc == 0) {
                int head = cy * 2 + hh;
                #pragma unroll
                for (int r = 0; r < 4; r++) {
                    int row = rowb + r;
                    if (row < N) { as1[row * 4 + head] = s[r]; ad1[row * 4 + head] = d[r]; }
                }
            }
        }
    }
}

// ---------------------------------------------------------------- layer-2 GEMM (MFMA) + fused att
// h2 = out1b[N][256](bf16, exact) @ W2[256][64] (hi/lo split -> 2 MFMA).
// Block: 256 rows x 64 cols. Wave: 64 rows. 4 mt x 4 ct x 8 kc.
__global__ __launch_bounds__(256) void k_gemm2(const ushort* __restrict__ xin,
                                               const ushort* __restrict__ w2hi,
                                               const ushort* __restrict__ w2lo,
                                               const float* __restrict__ atts,
                                               const float* __restrict__ attd,
                                               ushort* __restrict__ h2b,
                                               float* __restrict__ as2, float* __restrict__ ad2,
                                               int N) {
    __shared__ __align__(16) ushort lhi[16384];
    __shared__ __align__(16) ushort llo[16384];
    int tid = threadIdx.x;
    {
        float4* dh = (float4*)lhi; const float4* sh = (const float4*)w2hi;
        float4* dl = (float4*)llo; const float4* sl = (const float4*)w2lo;
        #pragma unroll
        for (int i = 0; i < 8; i++) {
            dh[tid + i * 256] = sh[tid + i * 256];
            dl[tid + i * 256] = sl[tid + i * 256];
        }
    }
    __syncthreads();
    int w = tid >> 6, l = tid & 63;
    int lc = l & 15, lk = l >> 4;
    int rbase = blockIdx.x * 256 + w * 64;

    f32x4 acc[4][4];
    #pragma unroll
    for (int mt = 0; mt < 4; mt++)
        #pragma unroll
        for (int ct = 0; ct < 4; ct++) acc[mt][ct] = (f32x4){0.f, 0.f, 0.f, 0.f};

    #pragma unroll
    for (int kc = 0; kc < 8; kc++) {
        BF8 a[4];
        #pragma unroll
        for (int mt = 0; mt < 4; mt++) {
            int row = rbase + mt * 16 + lc;
            if (row < N) {
                a[mt].v = *(const bf16x8*)(xin + (size_t)row * 256 + kc * 32 + lk * 8);
            } else {
                #pragma unroll
                for (int j = 0; j < 8; j++) a[mt].u[j] = 0;
            }
        }
        #pragma unroll
        for (int ct = 0; ct < 4; ct++) {
            int boff = ((ct * 8 + kc) * 64 + l) * 8;
            bf16x8 bhi = *(const bf16x8*)(lhi + boff);
            bf16x8 blo = *(const bf16x8*)(llo + boff);
            #pragma unroll
            for (int mt = 0; mt < 4; mt++) {
                acc[mt][ct] = __builtin_amdgcn_mfma_f32_16x16x32_bf16(a[mt].v, bhi, acc[mt][ct], 0, 0, 0);
                acc[mt][ct] = __builtin_amdgcn_mfma_f32_16x16x32_bf16(a[mt].v, blo, acc[mt][ct], 0, 0, 0);
            }
        }
    }
    #pragma unroll
    for (int mt = 0; mt < 4; mt++) {
        int rowb = rbase + mt * 16 + lk * 4;
        #pragma unroll
        for (int ct = 0; ct < 4; ct++) {
            int col = ct * 16 + lc;
            #pragma unroll
            for (int r = 0; r < 4; r++) {
                int row = rowb + r;
                if (row < N) h2b[(size_t)row * 64 + col] = f2bf(acc[mt][ct][r]);
            }
        }
        float s[4] = {0.f, 0.f, 0.f, 0.f}, d[4] = {0.f, 0.f, 0.f, 0.f};
        #pragma unroll
        for (int ct = 0; ct < 4; ct++) {
            int col = ct * 16 + lc;
            float av = atts[col], dv = attd[col];
            #pragma unroll
            for (int r = 0; r < 4; r++) { s[r] += acc[mt][ct][r] * av; d[r] += acc[mt][ct][r] * dv; }
        }
        #pragma unroll
        for (int r = 0; r < 4; r++) {
            #pragma unroll
            for (int off = 1; off < 16; off <<= 1) {
                s[r] += __shfl_xor(s[r], off);
                d[r] += __shfl_xor(d[r], off);
            }
        }
        if (lc == 0) {
            #pragma unroll
            for (int r = 0; r < 4; r++) {
                int row = rowb + r;
                if (row < N) { as2[row] = s[r]; ad2[row] = d[r]; }
            }
        }
    }
}

// ---------------------------------------------------------------- aggregation (1 wave / node, unroll 8)

__global__ __launch_bounds__(256) void k_agg1(const ushort* __restrict__ h1b,
                                              const float* __restrict__ as, const float* __restrict__ ad,
                                              const int* __restrict__ rowstart, const int* __restrict__ csr,
                                              const float* __restrict__ b1,
                                              ushort* __restrict__ out1b, int N) {
    int n = blockIdx.x * 4 + (threadIdx.x >> 6);
    int lane = threadIdx.x & 63;
    if (n >= N) return;
    int head = lane >> 4;
    int coff = lane * 4;
    float adv = ad[n * 4 + head];
    int beg = rowstart[n], end = rowstart[n + 1];
    float a0 = 0.f, a1 = 0.f, a2 = 0.f, a3 = 0.f, ssum = 0.f;
    int j = beg;
    for (; j + 8 <= end; j += 8) {
        int s[8];
        #pragma unroll
        for (int i = 0; i < 8; i++) s[i] = csr[j + i];
        float e[8];
        #pragma unroll
        for (int i = 0; i < 8; i++) e[i] = as[s[i] * 4 + head];
        ushort4 hv[8];
        #pragma unroll
        for (int i = 0; i < 8; i++) hv[i] = *(const ushort4*)(h1b + (size_t)s[i] * 256 + coff);
        #pragma unroll
        for (int i = 0; i < 8; i++) {
            float wv = edgew(e[i] + adv);
            ssum += wv;
            a0 += wv * bf2f(hv[i].x); a1 += wv * bf2f(hv[i].y);
            a2 += wv * bf2f(hv[i].z); a3 += wv * bf2f(hv[i].w);
        }
    }
    for (; j < end; j++) {
        int s0 = csr[j];
        float wv = edgew(as[s0 * 4 + head] + adv);
        ushort4 v0 = *(const ushort4*)(h1b + (size_t)s0 * 256 + coff);
        ssum += wv;
        a0 += wv * bf2f(v0.x); a1 += wv * bf2f(v0.y);
        a2 += wv * bf2f(v0.z); a3 += wv * bf2f(v0.w);
    }
    float inv = 1.f / ssum;
    float o0 = fmaxf(a0 * inv + b1[coff + 0], 0.f);
    float o1 = fmaxf(a1 * inv + b1[coff + 1], 0.f);
    float o2 = fmaxf(a2 * inv + b1[coff + 2], 0.f);
    float o3 = fmaxf(a3 * inv + b1[coff + 3], 0.f);
    ushort4 o;
    o.x = f2bf(o0); o.y = f2bf(o1); o.z = f2bf(o2); o.w = f2bf(o3);
    *(ushort4*)(out1b + (size_t)n * 256 + coff) = o;
}

__global__ __launch_bounds__(256) void k_agg2(const ushort* __restrict__ h2b,
                                              const float* __restrict__ as, const float* __restrict__ ad,
                                              const int* __restrict__ rowstart, const int* __restrict__ csr,
                                              const float* __restrict__ b2,
                                              float* __restrict__ out2, int N) {
    int n = blockIdx.x * 4 + (threadIdx.x >> 6);
    int lane = threadIdx.x & 63;
    if (n >= N) return;
    float adv = ad[n];
    int beg = rowstart[n], end = rowstart[n + 1];
    float acc = 0.f, ssum = 0.f;
    int j = beg;
    for (; j + 8 <= end; j += 8) {
        int s[8];
        #pragma unroll
        for (int i = 0; i < 8; i++) s[i] = csr[j + i];
        float e[8];
        #pragma unroll
        for (int i = 0; i < 8; i++) e[i] = as[s[i]];
        ushort hv[8];
        #pragma unroll
        for (int i = 0; i < 8; i++) hv[i] = h2b[(size_t)s[i] * 64 + lane];
        #pragma unroll
        for (int i = 0; i < 8; i++) {
            float wv = edgew(e[i] + adv);
            ssum += wv;
            acc += wv * bf2f(hv[i]);
        }
    }
    for (; j < end; j++) {
        int s0 = csr[j];
        float wv = edgew(as[s0] + adv);
        ssum += wv;
        acc += wv * bf2f(h2b[(size_t)s0 * 64 + lane]);
    }
    float o = acc / ssum + b2[lane];
    out2[(size_t)n * 64 + lane] = o > 0.f ? o : 0.f;
}

// ---------------------------------------------------------------- pool + final linear

__global__ __launch_bounds__(64) void k_pool(const float* __restrict__ out2,
                                             const int* __restrict__ gstart,
                                             const float* __restrict__ lin_w,
                                             const float* __restrict__ lin_b,
                                             float* __restrict__ out, int NG) {
    __shared__ float mean[64];
    int g = blockIdx.x;
    int lane = threadIdx.x;
    int beg = gstart[g], end = gstart[g + 1];
    float s = 0.f;
    for (int n = beg; n < end; n++) s += out2[(size_t)n * 64 + lane];
    float cnt = (float)(end - beg);
    mean[lane] = s / fmaxf(cnt, 1.f);
    __syncthreads();
    if (lane < NC) {
        float acc = lin_b[lane];
        #pragma unroll
        for (int c = 0; c < 64; c++) acc += mean[c] * lin_w[c * NC + lane];
        out[g * NC + lane] = acc;
    }
}

// ---------------------------------------------------------------- launch

extern "C" void kernel_launch(void* const* d_in, const int* in_sizes, int n_in,
                              void* d_out, int out_size, void* d_ws, size_t ws_size,
                              hipStream_t stream) {
    const float* x      = (const float*)d_in[0];
    const int*   ei     = (const int*)d_in[1];
    const int*   batch  = (const int*)d_in[2];
    const float* W1     = (const float*)d_in[3];
    const float* att_s1 = (const float*)d_in[4];
    const float* att_d1 = (const float*)d_in[5];
    const float* b1     = (const float*)d_in[6];
    const float* W2     = (const float*)d_in[7];
    const float* att_s2 = (const float*)d_in[8];
    const float* att_d2 = (const float*)d_in[9];
    const float* b2     = (const float*)d_in[10];
    const float* lin_w  = (const float*)d_in[11];
    const float* lin_b  = (const float*)d_in[12];
    float* out = (float*)d_out;

    const int N  = in_sizes[0] / F_IN;   // 50000
    const int E  = in_sizes[1] / 2;      // 800000
    const int NG = out_size / NC;        // 512
    const int NE = E + N;
    const int NB = (N + 1023) / 1024;    // scan blocks

    char* p = (char*)d_ws;
    auto alloc = [&](size_t bytes) { char* r = p; p += (bytes + 255) & ~(size_t)255; return r; };
    ushort* h1b     = (ushort*)alloc(sizeof(ushort) * (size_t)N * 256);
    ushort* out1b   = (ushort*)alloc(sizeof(ushort) * (size_t)N * 256);
    ushort* h2b     = (ushort*)alloc(sizeof(ushort) * (size_t)N * 64);
    float*  out2    = (float*)alloc(sizeof(float) * (size_t)N * 64);
    float*  as1     = (float*)alloc(sizeof(float) * (size_t)N * 4);
    float*  ad1     = (float*)alloc(sizeof(float) * (size_t)N * 4);
    float*  as2     = (float*)alloc(sizeof(float) * (size_t)N);
    float*  ad2     = (float*)alloc(sizeof(float) * (size_t)N);
    int*    rowstart= (int*)alloc(sizeof(int) * (size_t)(N + 1));
    int*    itmp    = (int*)alloc(sizeof(int) * (size_t)N);      // deg, then cursor
    int*    csr     = (int*)alloc(sizeof(int) * (size_t)NE);
    int*    counts  = (int*)alloc(sizeof(int) * (size_t)NG);
    int*    gstart  = (int*)alloc(sizeof(int) * (size_t)(NG + 1));
    int*    bsum    = (int*)alloc(sizeof(int) * 1024);
    int*    boff    = (int*)alloc(sizeof(int) * 1024);
    ushort* w1hi    = (ushort*)alloc(sizeof(ushort) * 32768);
    ushort* w1lo    = (ushort*)alloc(sizeof(ushort) * 32768);
    ushort* w2hi    = (ushort*)alloc(sizeof(ushort) * 16384);
    ushort* w2lo    = (ushort*)alloc(sizeof(ushort) * 16384);

    int bs = 256;
    // setup: W pack + deg/counts init (one kernel)
    k_setup<<<(N + bs - 1) / bs, bs, 0, stream>>>(W1, W2, w1hi, w1lo, w2hi, w2lo,
                                                  itmp, N, counts, NG);
    k_count<<<(E + bs - 1) / bs, bs, 0, stream>>>(ei, E, itmp, batch, N, counts);
    k_scan_part<<<NB, 1024, 0, stream>>>(itmp, rowstart, bsum, N);
    k_scan_small2<<<2, 1024, 0, stream>>>(bsum, boff, NB, rowstart + N, counts, gstart, NG);
    k_scan_add_self<<<(N + 1023) / 1024, 1024, 0, stream>>>(rowstart, boff, itmp, csr, N);
    k_scatter<<<(E + bs - 1) / bs, bs, 0, stream>>>(ei, E, rowstart, itmp, csr);

    // layer 1 (MFMA GEMM + fused att coefs), then aggregate (bf16 out)
    k_gemm1<<<dim3((N + 255) / 256, 2), 256, 0, stream>>>(x, w1hi, w1lo, att_s1, att_d1, h1b, as1, ad1, N);
    k_agg1<<<(N + 3) / 4, 256, 0, stream>>>(h1b, as1, ad1, rowstart, csr, b1, out1b, N);

    // layer 2 (bf16 A operand, 2-MFMA W split)
    k_gemm2<<<(N + 255) / 256, 256, 0, stream>>>(out1b, w2hi, w2lo, att_s2, att_d2, h2b, as2, ad2, N);
    k_agg2<<<(N + 3) / 4, 256, 0, stream>>>(h2b, as2, ad2, rowstart, csr, b2, out2, N);

    // pool + linear
    k_pool<<<NG, 64, 0, stream>>>(out2, gstart, lin_w, lin_b, out, NG);
}